// Round 8
// baseline (425.848 us; speedup 1.0000x reference)
//
#include <hip/hip_runtime.h>

#define H 10
#define T_LEN 2048
#define BATCH 8192

// row_ror:K within each 16-lane row: dst lane i reads src lane (i-K)&15.
// Direction verified on HW (rounds 1,3,4,5,6,7 all passed with this mapping).
#define MOVROR(x, K) __int_as_float(__builtin_amdgcn_mov_dpp(                    \
    __float_as_int(x), 0x120 + (K), 0xF, 0xF, true))

#define STR2(x) #x
#define VREG(n) "v" STR2(n)
#define DPP_(K) " row_ror:" STR2(K) " row_mask:0xf bank_mask:0xf\n\t"

// One recurrence step, 38 VALU instrs, ALL at full issue rate:
//   15 v_mov_b32_dpp (full-rate, proven by R4's 2.0 cy/instr average) into
//   v40..v54, then 16 plain v_fmac on two chains (v56,v57), then 4-op tail
//   (merge + abs()-modified add + max + bfi). The R6/R7 v_fmac+DPP fusion
//   measured ~6.7 cy/instr -- un-fusing trades 15 extra instrs for ~4.7 cy
//   saved on each of 15 ops.
// Hazards: first DPP read of h is 3 VALU after h's v_bfi write (>=2 needed).
// fmac consumers trail their mov by >=8 slots.
#define STEP(X0, X1)                                                \
    "v_mul_f32 v56, " VREG(X0) ", %[w0]\n\t"                        \
    "v_fmac_f32 v56, " VREG(X1) ", %[w1]\n\t"                       \
    "v_fmac_f32 v56, %[h], %[b0]\n\t"                               \
    "v_mov_b32_dpp v40, %[h]" DPP_(1)                               \
    "v_mov_b32_dpp v41, %[h]" DPP_(2)                               \
    "v_mov_b32_dpp v42, %[h]" DPP_(3)                               \
    "v_mov_b32_dpp v43, %[h]" DPP_(4)                               \
    "v_mov_b32_dpp v44, %[h]" DPP_(5)                               \
    "v_mov_b32_dpp v45, %[h]" DPP_(6)                               \
    "v_mov_b32_dpp v46, %[h]" DPP_(7)                               \
    "v_mov_b32_dpp v47, %[h]" DPP_(8)                               \
    "v_mov_b32_dpp v48, %[h]" DPP_(9)                               \
    "v_mov_b32_dpp v49, %[h]" DPP_(10)                              \
    "v_mov_b32_dpp v50, %[h]" DPP_(11)                              \
    "v_mov_b32_dpp v51, %[h]" DPP_(12)                              \
    "v_mov_b32_dpp v52, %[h]" DPP_(13)                              \
    "v_mov_b32_dpp v53, %[h]" DPP_(14)                              \
    "v_mov_b32_dpp v54, %[h]" DPP_(15)                              \
    "v_mul_f32 v57, v47, %[b8]\n\t"                                 \
    "v_fmac_f32 v56, v40, %[b1]\n\t"                                \
    "v_fmac_f32 v57, v48, %[b9]\n\t"                                \
    "v_fmac_f32 v56, v41, %[b2]\n\t"                                \
    "v_fmac_f32 v57, v49, %[b10]\n\t"                               \
    "v_fmac_f32 v56, v42, %[b3]\n\t"                                \
    "v_fmac_f32 v57, v50, %[b11]\n\t"                               \
    "v_fmac_f32 v56, v43, %[b4]\n\t"                                \
    "v_fmac_f32 v57, v51, %[b12]\n\t"                               \
    "v_fmac_f32 v56, v44, %[b5]\n\t"                                \
    "v_fmac_f32 v57, v52, %[b13]\n\t"                               \
    "v_fmac_f32 v56, v45, %[b6]\n\t"                                \
    "v_fmac_f32 v57, v53, %[b14]\n\t"                               \
    "v_fmac_f32 v56, v46, %[b7]\n\t"                                \
    "v_fmac_f32 v57, v54, %[b15]\n\t"                               \
    "v_add_f32 v56, v56, v57\n\t"                                   \
    "v_add_f32 v57, abs(v56), %[bm]\n\t"                            \
    "v_max_f32 v57, 0, v57\n\t"                                     \
    "v_bfi_b32 %[h], %[mk], v57, v56\n\t"

// Sub-iter control: issue 4 dwordx4 into the buffer 3 sub-iters ahead,
// counted wait vmcnt(12). Last 3 sub-iters (it>=253) skip issue and drain.
#define SUBCTL(TAG, LD0, LD1, LD2, LD3)                             \
    "s_cmp_lt_u32 %[it], 253\n\t"                                   \
    "s_cbranch_scc0 Lsk" TAG "_%=\n\t"                              \
    "global_load_dwordx4 " LD0 ", v[60:61], off\n\t"                \
    "global_load_dwordx4 " LD1 ", v[60:61], off offset:16\n\t"      \
    "global_load_dwordx4 " LD2 ", v[60:61], off offset:32\n\t"      \
    "global_load_dwordx4 " LD3 ", v[60:61], off offset:48\n\t"      \
    "v_add_co_u32 v60, vcc, 64, v60\n\t"                            \
    "v_addc_co_u32 v61, vcc, 0, v61, vcc\n\t"                       \
    "s_waitcnt vmcnt(12)\n\t"                                       \
    "s_branch Ldn" TAG "_%=\n\t"                                    \
    "Lsk" TAG "_%=:\n\t"                                            \
    "s_waitcnt vmcnt(0)\n\t"                                        \
    "Ldn" TAG "_%=:\n\t"                                            \
    "s_add_i32 %[it], %[it], 1\n\t"

// ---------------------------------------------------------------------------
// Single fused kernel: every block computes the 10x10 expm redundantly in
// fp64 LDS (~1-2 us, parallel across blocks; op-for-op identical to the old
// standalone kernel => bit-identical B), then runs the hand-asm recurrence.
// Removes one kernel launch + the inter-kernel dependency gap.
// 16 lanes/batch (h[j] per lane, H 10->16, pads provably stay 0), 4 batches/
// wave, 2048 waves = 2/SIMD. 4 fixed x-buffers v64..v127 (8 steps each),
// depth-3 prefetch, counted s_waitcnt vmcnt(12).
// ---------------------------------------------------------------------------
__global__ __launch_bounds__(64, 2)
void rnn_kernel(const float* __restrict__ x,
                const float* __restrict__ A,
                const float* __restrict__ Win,
                const float* __restrict__ bmod,
                const float* __restrict__ lW,
                const float* __restrict__ lb,
                float* __restrict__ out) {
    __shared__ double S[H][H];
    __shared__ double Pm[H][H];
    __shared__ double E[H][H];
    const int tid = threadIdx.x;

    // ---- expm(skew(A)) in fp64: scaling 2^-8, 16 Taylor terms, 8 squarings.
    // Elements e0 = tid (always < 100) and e1 = tid + 64 (valid for tid < 36).
    {
        const int e0 = tid, e1 = tid + 64;
        const int i0 = e0 / H, j0 = e0 % H;
        const int i1 = e1 / H, j1 = e1 % H;
        const bool v1 = (e1 < H * H);
        double a0 = 0.0;
        if (i0 < j0) a0 = (double)A[i0 * H + j0];
        else if (i0 > j0) a0 = -(double)A[j0 * H + i0];
        a0 *= (1.0 / 256.0);
        S[i0][j0] = a0; Pm[i0][j0] = a0;
        E[i0][j0] = (i0 == j0 ? 1.0 : 0.0) + a0;
        if (v1) {
            double a1 = 0.0;
            if (i1 < j1) a1 = (double)A[i1 * H + j1];
            else if (i1 > j1) a1 = -(double)A[j1 * H + i1];
            a1 *= (1.0 / 256.0);
            S[i1][j1] = a1; Pm[i1][j1] = a1;
            E[i1][j1] = (i1 == j1 ? 1.0 : 0.0) + a1;
        }
        __syncthreads();
        for (int k = 2; k <= 16; ++k) {
            double t0 = 0.0, t1 = 0.0;
            for (int m = 0; m < H; ++m) t0 += Pm[i0][m] * S[m][j0];
            t0 *= (1.0 / (double)k);
            if (v1) {
                for (int m = 0; m < H; ++m) t1 += Pm[i1][m] * S[m][j1];
                t1 *= (1.0 / (double)k);
            }
            __syncthreads();
            Pm[i0][j0] = t0; E[i0][j0] += t0;
            if (v1) { Pm[i1][j1] = t1; E[i1][j1] += t1; }
            __syncthreads();
        }
        for (int rr = 0; rr < 8; ++rr) {
            double t0 = 0.0, t1 = 0.0;
            for (int m = 0; m < H; ++m) t0 += E[i0][m] * E[m][j0];
            if (v1) {
                for (int m = 0; m < H; ++m) t1 += E[i1][m] * E[m][j1];
            }
            __syncthreads();
            E[i0][j0] = t0;
            if (v1) E[i1][j1] = t1;
            __syncthreads();
        }
    }

    // ---- recurrence setup
    const int j    = tid & 15;           // owned h component
    const int row  = tid >> 4;           // 0..3: batch within wave
    const int bb   = blockIdx.x * 4 + row;   // 8192 = 2048*4 exact

    // Rotation k delivers h[(j-k)&15]; Bv[k] = B[(j-k)&15][j] (0 on pads).
    float Bv[16];
#pragma unroll
    for (int k = 0; k < 16; ++k) {
        const int m = (j - k) & 15;
        Bv[k] = (j < H && m < H) ? (float)E[m][j] : 0.f;
    }
    float w0j = 0.f, w1j = 0.f, bmj = 0.f;
    if (j < H) { w0j = Win[j * 2]; w1j = Win[j * 2 + 1]; bmj = bmod[j]; }

    float h = 0.f;
    int it = 0;
    const uint64_t addr = (uint64_t)(x + (size_t)bb * (T_LEN * 2));
    const unsigned alo = (unsigned)addr, ahi = (unsigned)(addr >> 32);

    asm volatile(
        // addr regs + prologue: stage bufs 0..2 (12 loads, 192 B)
        "v_mov_b32 v60, %[alo]\n\t"
        "v_mov_b32 v61, %[ahi]\n\t"
        "global_load_dwordx4 v[64:67],   v[60:61], off\n\t"
        "global_load_dwordx4 v[68:71],   v[60:61], off offset:16\n\t"
        "global_load_dwordx4 v[72:75],   v[60:61], off offset:32\n\t"
        "global_load_dwordx4 v[76:79],   v[60:61], off offset:48\n\t"
        "global_load_dwordx4 v[80:83],   v[60:61], off offset:64\n\t"
        "global_load_dwordx4 v[84:87],   v[60:61], off offset:80\n\t"
        "global_load_dwordx4 v[88:91],   v[60:61], off offset:96\n\t"
        "global_load_dwordx4 v[92:95],   v[60:61], off offset:112\n\t"
        "global_load_dwordx4 v[96:99],   v[60:61], off offset:128\n\t"
        "global_load_dwordx4 v[100:103], v[60:61], off offset:144\n\t"
        "global_load_dwordx4 v[104:107], v[60:61], off offset:160\n\t"
        "global_load_dwordx4 v[108:111], v[60:61], off offset:176\n\t"
        "v_add_co_u32 v60, vcc, 0xc0, v60\n\t"
        "v_addc_co_u32 v61, vcc, 0, v61, vcc\n\t"
        "Lmain_%=:\n\t"
        // sub0: reads buf0 (v64-79), issues buf3 (v112-127)
        SUBCTL("0", "v[112:115]", "v[116:119]", "v[120:123]", "v[124:127]")
        STEP(64, 65)  STEP(66, 67)  STEP(68, 69)  STEP(70, 71)
        STEP(72, 73)  STEP(74, 75)  STEP(76, 77)  STEP(78, 79)
        // sub1: reads buf1 (v80-95), issues buf0 (v64-79)
        SUBCTL("1", "v[64:67]", "v[68:71]", "v[72:75]", "v[76:79]")
        STEP(80, 81)  STEP(82, 83)  STEP(84, 85)  STEP(86, 87)
        STEP(88, 89)  STEP(90, 91)  STEP(92, 93)  STEP(94, 95)
        // sub2: reads buf2 (v96-111), issues buf1 (v80-95)
        SUBCTL("2", "v[80:83]", "v[84:87]", "v[88:91]", "v[92:95]")
        STEP(96, 97)  STEP(98, 99)  STEP(100, 101) STEP(102, 103)
        STEP(104, 105) STEP(106, 107) STEP(108, 109) STEP(110, 111)
        // sub3: reads buf3 (v112-127), issues buf2 (v96-111)
        SUBCTL("3", "v[96:99]", "v[100:103]", "v[104:107]", "v[108:111]")
        STEP(112, 113) STEP(114, 115) STEP(116, 117) STEP(118, 119)
        STEP(120, 121) STEP(122, 123) STEP(124, 125) STEP(126, 127)
        "s_cmp_lg_u32 %[it], 256\n\t"
        "s_cbranch_scc1 Lmain_%=\n\t"
        : [h] "+v"(h), [it] "+s"(it)
        : [alo] "v"(alo), [ahi] "v"(ahi),
          [w0] "v"(w0j), [w1] "v"(w1j), [bm] "v"(bmj),
          [mk] "s"(0x7fffffffu),
          [b0] "v"(Bv[0]),  [b1] "v"(Bv[1]),  [b2] "v"(Bv[2]),  [b3] "v"(Bv[3]),
          [b4] "v"(Bv[4]),  [b5] "v"(Bv[5]),  [b6] "v"(Bv[6]),  [b7] "v"(Bv[7]),
          [b8] "v"(Bv[8]),  [b9] "v"(Bv[9]),  [b10] "v"(Bv[10]), [b11] "v"(Bv[11]),
          [b12] "v"(Bv[12]), [b13] "v"(Bv[13]), [b14] "v"(Bv[14]), [b15] "v"(Bv[15])
        : "memory", "vcc", "scc",
          "v40", "v41", "v42", "v43", "v44", "v45", "v46", "v47", "v48", "v49",
          "v50", "v51", "v52", "v53", "v54", "v55", "v56", "v57",
          "v60", "v61",
          "v64", "v65", "v66", "v67", "v68", "v69",
          "v70", "v71", "v72", "v73", "v74", "v75", "v76", "v77", "v78", "v79",
          "v80", "v81", "v82", "v83", "v84", "v85", "v86", "v87", "v88", "v89",
          "v90", "v91", "v92", "v93", "v94", "v95", "v96", "v97", "v98", "v99",
          "v100", "v101", "v102", "v103", "v104", "v105", "v106", "v107",
          "v108", "v109", "v110", "v111", "v112", "v113", "v114", "v115",
          "v116", "v117", "v118", "v119", "v120", "v121", "v122", "v123",
          "v124", "v125", "v126", "v127");

    // epilogue: out[bb][j] = lb[j] + sum_m h[m] * lW[j][m] (cold; builtin DPP)
    float Lrot[16];
#pragma unroll
    for (int k = 0; k < 16; ++k) {
        const int m = (j - k) & 15;
        Lrot[k] = (j < H && m < H) ? lW[j * H + m] : 0.f;
    }
    float acc = (j < H) ? lb[j] : 0.f;
    acc = fmaf(h, Lrot[0], acc);
#define OUTK(K) { const float e_ = MOVROR(h, K); acc = fmaf(e_, Lrot[K], acc); }
    OUTK(1)  OUTK(2)  OUTK(3)  OUTK(4)  OUTK(5)
    OUTK(6)  OUTK(7)  OUTK(8)  OUTK(9)  OUTK(10)
    OUTK(11) OUTK(12) OUTK(13) OUTK(14) OUTK(15)
#undef OUTK
    if (j < H) out[(size_t)bb * H + j] = acc;
}

extern "C" void kernel_launch(void* const* d_in, const int* in_sizes, int n_in,
                              void* d_out, int out_size, void* d_ws, size_t ws_size,
                              hipStream_t stream) {
    const float* inputs = (const float*)d_in[0];  // [8192, 2048, 2]
    const float* A      = (const float*)d_in[1];  // [10, 10]
    const float* W_in   = (const float*)d_in[2];  // [10, 2]
    const float* b_mod  = (const float*)d_in[3];  // [10]
    const float* lin_W  = (const float*)d_in[4];  // [10, 10]
    const float* lin_b  = (const float*)d_in[5];  // [10]
    float* out = (float*)d_out;                   // [8192, 10]
    (void)d_ws; (void)ws_size;

    rnn_kernel<<<BATCH / 4, 64, 0, stream>>>(inputs, A, W_in, b_mod,
                                             lin_W, lin_b, out);
}

// Round 9
// 327.459 us; speedup vs baseline: 1.3005x; 1.3005x over previous
//
#include <hip/hip_runtime.h>

#define H 10
#define T_LEN 2048
#define BATCH 8192

typedef float v2f __attribute__((ext_vector_type(2)));
__device__ __forceinline__ v2f vdup(float s) { v2f r; r.x = s; r.y = s; return r; }
__device__ __forceinline__ v2f vfma2(v2f a, v2f b, v2f c) {
    return __builtin_elementwise_fma(a, b, c);
}
// row_ror:(2K) within 16-lane rows: rotates q by K preserving parity (HW-verified R1/R3).
#define ROR2K(x, K) __int_as_float(__builtin_amdgcn_update_dpp(                  \
    0, __float_as_int(x), 0x120 + 2 * (K), 0xF, 0xF, true))

#define STR2(x) #x
#define XP(A, B) "v[" STR2(A) ":" STR2(B) "]"
#define MRD(D, S, N) "v_mov_b32_dpp " D ", " S " row_ror:" STR2(N)              \
                     " row_mask:0xf bank_mask:0xf\n\t"
#define SW " op_sel:[1,0,0] op_sel_hi:[0,1,1]\n\t"   // src0 halves swapped (HW-verified R3)

// Hand regs: h=v[48:49], rtA=v[50:51], rtB=v[52:53], accP=v[54:55],
// accQ=v[56:57], tmp=v58/59, addr=v[60:61], x-buffers v64..v127.
// One step = 39 VALU: 2 packed xproj + 16 pk_fma + 14 mov_dpp + merge + 6 tail.
// Serves 8 batches -> 4.9 instr/batch (16-lane layout was 5.8).
// Hazards: first DPP read of h (pos5) is 4 instrs after h's v_bfi write ok.
#define STEP(A, B)                                                              \
 "v_pk_mul_f32 v[54:55], " XP(A,B) ", %[w0] op_sel:[0,0] op_sel_hi:[0,1]\n\t"   \
 "v_pk_fma_f32 v[54:55], " XP(A,B) ", %[w1], v[54:55] op_sel:[1,0,0] op_sel_hi:[1,1,1]\n\t" \
 "v_pk_fma_f32 v[54:55], v[48:49], %[bn0], v[54:55]\n\t"                        \
 "v_pk_fma_f32 v[54:55], v[48:49], %[bs0], v[54:55]" SW                         \
 MRD("v50","v48",2)  MRD("v51","v49",2)                                         \
 MRD("v52","v48",4)  MRD("v53","v49",4)                                         \
 "v_pk_fma_f32 v[54:55], v[50:51], %[bn1], v[54:55]\n\t"                        \
 "v_pk_fma_f32 v[54:55], v[50:51], %[bs1], v[54:55]" SW                         \
 MRD("v50","v48",6)  MRD("v51","v49",6)                                         \
 "v_pk_fma_f32 v[54:55], v[52:53], %[bn2], v[54:55]\n\t"                        \
 "v_pk_fma_f32 v[54:55], v[52:53], %[bs2], v[54:55]" SW                         \
 MRD("v52","v48",8)  MRD("v53","v49",8)                                         \
 "v_pk_fma_f32 v[54:55], v[50:51], %[bn3], v[54:55]\n\t"                        \
 "v_pk_fma_f32 v[54:55], v[50:51], %[bs3], v[54:55]" SW                         \
 MRD("v50","v48",10) MRD("v51","v49",10)                                        \
 "v_pk_mul_f32 v[56:57], v[52:53], %[bn4]\n\t"                                  \
 "v_pk_fma_f32 v[56:57], v[52:53], %[bs4], v[56:57]" SW                         \
 MRD("v52","v48",12) MRD("v53","v49",12)                                        \
 "v_pk_fma_f32 v[56:57], v[50:51], %[bn5], v[56:57]\n\t"                        \
 "v_pk_fma_f32 v[56:57], v[50:51], %[bs5], v[56:57]" SW                         \
 MRD("v50","v48",14) MRD("v51","v49",14)                                        \
 "v_pk_fma_f32 v[56:57], v[52:53], %[bn6], v[56:57]\n\t"                        \
 "v_pk_fma_f32 v[56:57], v[52:53], %[bs6], v[56:57]" SW                         \
 "v_pk_fma_f32 v[56:57], v[50:51], %[bn7], v[56:57]\n\t"                        \
 "v_pk_fma_f32 v[56:57], v[50:51], %[bs7], v[56:57]" SW                         \
 "v_pk_add_f32 v[54:55], v[54:55], v[56:57]\n\t"                                \
 "v_add_f32 v58, abs(v54), %[bm0]\n\t"                                          \
 "v_add_f32 v59, abs(v55), %[bm1]\n\t"                                          \
 "v_max_f32 v58, 0, v58\n\t"                                                    \
 "v_max_f32 v59, 0, v59\n\t"                                                    \
 "v_bfi_b32 v48, %[mk], v58, v54\n\t"                                           \
 "v_bfi_b32 v49, %[mk], v59, v55\n\t"

// Proven R6 sub-iter control: 4 dwordx4 issued 3 sub-iters ahead, vmcnt(12).
#define SUBCTL(TAG, LD0, LD1, LD2, LD3)                             \
    "s_cmp_lt_u32 %[it], 253\n\t"                                   \
    "s_cbranch_scc0 Lsk" TAG "_%=\n\t"                              \
    "global_load_dwordx4 " LD0 ", v[60:61], off\n\t"                \
    "global_load_dwordx4 " LD1 ", v[60:61], off offset:16\n\t"      \
    "global_load_dwordx4 " LD2 ", v[60:61], off offset:32\n\t"      \
    "global_load_dwordx4 " LD3 ", v[60:61], off offset:48\n\t"      \
    "v_add_co_u32 v60, vcc, 64, v60\n\t"                            \
    "v_addc_co_u32 v61, vcc, 0, v61, vcc\n\t"                       \
    "s_waitcnt vmcnt(12)\n\t"                                       \
    "s_branch Ldn" TAG "_%=\n\t"                                    \
    "Lsk" TAG "_%=:\n\t"                                            \
    "s_waitcnt vmcnt(0)\n\t"                                        \
    "Ldn" TAG "_%=:\n\t"                                            \
    "s_add_i32 %[it], %[it], 1\n\t"

// ---------------------------------------------------------------------------
// Single fused kernel: per-block fp64 expm (verified R8, bit-identical B),
// then the hand-asm packed recurrence. 8 lanes/batch (R1/R3 layout: 16-lane
// rows, 2 batches interleaved even/odd, lane q=(l16)>>1 owns h[2q],h[2q+1],
// H padded 10->16, pads provably stay 0). 8 batches/wave, 1024 waves = 1/SIMD.
// ---------------------------------------------------------------------------
__global__ __launch_bounds__(64, 1)
void rnn_kernel(const float* __restrict__ x,
                const float* __restrict__ A,
                const float* __restrict__ Win,
                const float* __restrict__ bmod,
                const float* __restrict__ lW,
                const float* __restrict__ lb,
                float* __restrict__ out) {
    __shared__ double S[H][H];
    __shared__ double Pm[H][H];
    __shared__ double E[H][H];
    const int tid = threadIdx.x;

    // ---- expm(skew(A)) fp64: scale 2^-8, 16 Taylor terms, 8 squarings (R8).
    {
        const int e0 = tid, e1 = tid + 64;
        const int i0 = e0 / H, j0 = e0 % H;
        const int i1 = e1 / H, j1 = e1 % H;
        const bool v1 = (e1 < H * H);
        double a0 = 0.0;
        if (i0 < j0) a0 = (double)A[i0 * H + j0];
        else if (i0 > j0) a0 = -(double)A[j0 * H + i0];
        a0 *= (1.0 / 256.0);
        S[i0][j0] = a0; Pm[i0][j0] = a0;
        E[i0][j0] = (i0 == j0 ? 1.0 : 0.0) + a0;
        if (v1) {
            double a1 = 0.0;
            if (i1 < j1) a1 = (double)A[i1 * H + j1];
            else if (i1 > j1) a1 = -(double)A[j1 * H + i1];
            a1 *= (1.0 / 256.0);
            S[i1][j1] = a1; Pm[i1][j1] = a1;
            E[i1][j1] = (i1 == j1 ? 1.0 : 0.0) + a1;
        }
        __syncthreads();
        for (int k = 2; k <= 16; ++k) {
            double t0 = 0.0, t1 = 0.0;
            for (int m = 0; m < H; ++m) t0 += Pm[i0][m] * S[m][j0];
            t0 *= (1.0 / (double)k);
            if (v1) {
                for (int m = 0; m < H; ++m) t1 += Pm[i1][m] * S[m][j1];
                t1 *= (1.0 / (double)k);
            }
            __syncthreads();
            Pm[i0][j0] = t0; E[i0][j0] += t0;
            if (v1) { Pm[i1][j1] = t1; E[i1][j1] += t1; }
            __syncthreads();
        }
        for (int rr = 0; rr < 8; ++rr) {
            double t0 = 0.0, t1 = 0.0;
            for (int m = 0; m < H; ++m) t0 += E[i0][m] * E[m][j0];
            if (v1) {
                for (int m = 0; m < H; ++m) t1 += E[i1][m] * E[m][j1];
            }
            __syncthreads();
            E[i0][j0] = t0;
            if (v1) E[i1][j1] = t1;
            __syncthreads();
        }
    }

    // ---- packed layout setup (R3-verified mapping)
    const int l16 = tid & 15;
    const int row = tid >> 4;            // 0..3
    const int par = l16 & 1;             // batch parity in the row
    const int q   = l16 >> 1;            // 0..7 comb position
    const int bb  = blockIdx.x * 8 + row * 2 + par;   // 8192 = 1024*8 exact
    const int o0  = 2 * q, o1 = o0 + 1;

    // Bn[k]={B[j0][o0],B[j1][o1]}, Bs[k]={B[j1][o0],B[j0][o1]}, j0=2m,j1=2m+1,
    // m=(q-k)&7 (rotation k delivers source pair m). 0 on pads.
    v2f Bn[8], Bs[8];
#pragma unroll
    for (int k = 0; k < 8; ++k) {
        const int m = (q - k) & 7;
        const int j0 = 2 * m, j1 = j0 + 1;
        v2f bn = vdup(0.f), bs = vdup(0.f);
        if (o0 < H) {
            if (j0 < H) bn.x = (float)E[j0][o0];
            if (j1 < H) bs.x = (float)E[j1][o0];
        }
        if (o1 < H) {
            if (j1 < H) bn.y = (float)E[j1][o1];
            if (j0 < H) bs.y = (float)E[j0][o1];
        }
        Bn[k] = bn; Bs[k] = bs;
    }
    v2f w0v = vdup(0.f), w1v = vdup(0.f);
    float bm0 = 0.f, bm1 = 0.f;
    if (o0 < H) { w0v.x = Win[o0 * 2]; w1v.x = Win[o0 * 2 + 1]; bm0 = bmod[o0]; }
    if (o1 < H) { w0v.y = Win[o1 * 2]; w1v.y = Win[o1 * 2 + 1]; bm1 = bmod[o1]; }

    float hx, hy;
    int it = 0;
    const uint64_t addr = (uint64_t)(x + (size_t)bb * (T_LEN * 2));
    const unsigned alo = (unsigned)addr, ahi = (unsigned)(addr >> 32);

    asm volatile(
        "v_mov_b32 v48, 0\n\t"
        "v_mov_b32 v49, 0\n\t"
        "v_mov_b32 v60, %[alo]\n\t"
        "v_mov_b32 v61, %[ahi]\n\t"
        "global_load_dwordx4 v[64:67],   v[60:61], off\n\t"
        "global_load_dwordx4 v[68:71],   v[60:61], off offset:16\n\t"
        "global_load_dwordx4 v[72:75],   v[60:61], off offset:32\n\t"
        "global_load_dwordx4 v[76:79],   v[60:61], off offset:48\n\t"
        "global_load_dwordx4 v[80:83],   v[60:61], off offset:64\n\t"
        "global_load_dwordx4 v[84:87],   v[60:61], off offset:80\n\t"
        "global_load_dwordx4 v[88:91],   v[60:61], off offset:96\n\t"
        "global_load_dwordx4 v[92:95],   v[60:61], off offset:112\n\t"
        "global_load_dwordx4 v[96:99],   v[60:61], off offset:128\n\t"
        "global_load_dwordx4 v[100:103], v[60:61], off offset:144\n\t"
        "global_load_dwordx4 v[104:107], v[60:61], off offset:160\n\t"
        "global_load_dwordx4 v[108:111], v[60:61], off offset:176\n\t"
        "v_add_co_u32 v60, vcc, 0xc0, v60\n\t"
        "v_addc_co_u32 v61, vcc, 0, v61, vcc\n\t"
        "Lmain_%=:\n\t"
        SUBCTL("0", "v[112:115]", "v[116:119]", "v[120:123]", "v[124:127]")
        STEP(64, 65)  STEP(66, 67)  STEP(68, 69)  STEP(70, 71)
        STEP(72, 73)  STEP(74, 75)  STEP(76, 77)  STEP(78, 79)
        SUBCTL("1", "v[64:67]", "v[68:71]", "v[72:75]", "v[76:79]")
        STEP(80, 81)  STEP(82, 83)  STEP(84, 85)  STEP(86, 87)
        STEP(88, 89)  STEP(90, 91)  STEP(92, 93)  STEP(94, 95)
        SUBCTL("2", "v[80:83]", "v[84:87]", "v[88:91]", "v[92:95]")
        STEP(96, 97)   STEP(98, 99)   STEP(100, 101) STEP(102, 103)
        STEP(104, 105) STEP(106, 107) STEP(108, 109) STEP(110, 111)
        SUBCTL("3", "v[96:99]", "v[100:103]", "v[104:107]", "v[108:111]")
        STEP(112, 113) STEP(114, 115) STEP(116, 117) STEP(118, 119)
        STEP(120, 121) STEP(122, 123) STEP(124, 125) STEP(126, 127)
        "s_cmp_lg_u32 %[it], 256\n\t"
        "s_cbranch_scc1 Lmain_%=\n\t"
        "v_mov_b32 %[hx], v48\n\t"
        "v_mov_b32 %[hy], v49\n\t"
        : [hx] "=&v"(hx), [hy] "=&v"(hy), [it] "+s"(it)
        : [alo] "v"(alo), [ahi] "v"(ahi),
          [w0] "v"(w0v), [w1] "v"(w1v), [bm0] "v"(bm0), [bm1] "v"(bm1),
          [mk] "s"(0x7fffffffu),
          [bn0] "v"(Bn[0]), [bn1] "v"(Bn[1]), [bn2] "v"(Bn[2]), [bn3] "v"(Bn[3]),
          [bn4] "v"(Bn[4]), [bn5] "v"(Bn[5]), [bn6] "v"(Bn[6]), [bn7] "v"(Bn[7]),
          [bs0] "v"(Bs[0]), [bs1] "v"(Bs[1]), [bs2] "v"(Bs[2]), [bs3] "v"(Bs[3]),
          [bs4] "v"(Bs[4]), [bs5] "v"(Bs[5]), [bs6] "v"(Bs[6]), [bs7] "v"(Bs[7])
        : "memory", "vcc", "scc",
          "v48", "v49", "v50", "v51", "v52", "v53", "v54", "v55", "v56", "v57",
          "v58", "v59", "v60", "v61",
          "v64", "v65", "v66", "v67", "v68", "v69", "v70", "v71",
          "v72", "v73", "v74", "v75", "v76", "v77", "v78", "v79",
          "v80", "v81", "v82", "v83", "v84", "v85", "v86", "v87",
          "v88", "v89", "v90", "v91", "v92", "v93", "v94", "v95",
          "v96", "v97", "v98", "v99", "v100", "v101", "v102", "v103",
          "v104", "v105", "v106", "v107", "v108", "v109", "v110", "v111",
          "v112", "v113", "v114", "v115", "v116", "v117", "v118", "v119",
          "v120", "v121", "v122", "v123", "v124", "v125", "v126", "v127");

    // epilogue (cold, R3-verified): out[bb][o] = lb[o] + sum_j h_j*lW[o][j]
    v2f L0[8], L1[8];
#pragma unroll
    for (int k = 0; k < 8; ++k) {
        const int m = (q - k) & 7;
        const int j0 = 2 * m, j1 = j0 + 1;
        v2f a0 = vdup(0.f), a1 = vdup(0.f);
        if (o0 < H) {
            if (j0 < H) a0.x = lW[o0 * H + j0];
            if (j1 < H) a1.x = lW[o0 * H + j1];
        }
        if (o1 < H) {
            if (j0 < H) a0.y = lW[o1 * H + j0];
            if (j1 < H) a1.y = lW[o1 * H + j1];
        }
        L0[k] = a0; L1[k] = a1;
    }
    v2f accO = vdup(0.f);
    if (o0 < H) accO.x = lb[o0];
    if (o1 < H) accO.y = lb[o1];
    accO = vfma2(vdup(hx), L0[0], accO);
    accO = vfma2(vdup(hy), L1[0], accO);
#define OUTK(K) { const float ex_ = ROR2K(hx, K); const float ey_ = ROR2K(hy, K); \
                  accO = vfma2(vdup(ex_), L0[K], accO);                           \
                  accO = vfma2(vdup(ey_), L1[K], accO); }
    OUTK(1) OUTK(2) OUTK(3) OUTK(4) OUTK(5) OUTK(6) OUTK(7)
#undef OUTK
    if (o0 < H) {
        float2 st; st.x = accO.x; st.y = accO.y;
        *reinterpret_cast<float2*>(out + (size_t)bb * H + o0) = st;
    }
}

extern "C" void kernel_launch(void* const* d_in, const int* in_sizes, int n_in,
                              void* d_out, int out_size, void* d_ws, size_t ws_size,
                              hipStream_t stream) {
    const float* inputs = (const float*)d_in[0];  // [8192, 2048, 2]
    const float* A      = (const float*)d_in[1];  // [10, 10]
    const float* W_in   = (const float*)d_in[2];  // [10, 2]
    const float* b_mod  = (const float*)d_in[3];  // [10]
    const float* lin_W  = (const float*)d_in[4];  // [10, 10]
    const float* lin_b  = (const float*)d_in[5];  // [10]
    float* out = (float*)d_out;                   // [8192, 10]
    (void)d_ws; (void)ws_size;

    rnn_kernel<<<BATCH / 8, 64, 0, stream>>>(inputs, A, W_in, b_mod,
                                             lin_W, lin_b, out);
}